// Round 2
// baseline (287.707 us; speedup 1.0000x reference)
//
#include <hip/hip_runtime.h>
#include <stdint.h>

#define D_DIM 128
#define NROW 8192
#define MROW 8192
#define TILE 128
#define OUT_LD 8192

typedef __bf16 bf16x8 __attribute__((ext_vector_type(8)));
typedef float f32x4 __attribute__((ext_vector_type(4)));
typedef unsigned short u16x8 __attribute__((ext_vector_type(8)));

__device__ __forceinline__ unsigned short f32_to_bf16(float f) {
    uint32_t u = __float_as_uint(f);
    u = (u + 0x7FFFu + ((u >> 16) & 1u)) >> 16;   // round-to-nearest-even
    return (unsigned short)u;
}

// Pack X,Y -> bf16 in MFMA-fragment order AND compute exact f32 row norms.
// Packed unit u (16 B = 8 bf16) within a matrix:
//   u = (((tt*8 + ti)*4 + ks)*4 + quad)*16 + l16
//   source: row = tt*128 + ti*16 + l16, k = ks*32 + quad*8 .. +7
// In the main kernel, a wave's fragment load for (group, ks) is then
// base + lane*16 -> one fully-coalesced 1 KB global_load_dwordx4 per fragment,
// directly in MFMA operand layout (quad = k-quad, l16 = row-in-16-group).
__global__ __launch_bounds__(256) void rbf_pack(const float* __restrict__ X,
                                                const float* __restrict__ Y,
                                                unsigned short* __restrict__ Xt,
                                                unsigned short* __restrict__ Yt,
                                                float* __restrict__ nrm) {
    __shared__ float part[4][16];
    const int t = threadIdx.x;
    const int gid = blockIdx.x * 256 + t;
    const int mat = gid >> 17;          // 131072 units per matrix
    const int u = gid & 131071;
    const int tt = u >> 11;             // 128-row tile
    const int ti = (u >> 8) & 7;        // 16-row group (block-uniform)
    const int ks = (u >> 6) & 3;        // K-step of 32  (== wave id in block)
    const int quad = (u >> 4) & 3;      // k-quad of 8
    const int l16 = u & 15;
    const int row = tt * 128 + ti * 16 + l16;

    const float* src = (mat ? Y : X) + (size_t)row * D_DIM + ks * 32 + quad * 8;
    float4 a = *(const float4*)src;
    float4 b = *(const float4*)(src + 4);
    u16x8 h = { f32_to_bf16(a.x), f32_to_bf16(a.y), f32_to_bf16(a.z), f32_to_bf16(a.w),
                f32_to_bf16(b.x), f32_to_bf16(b.y), f32_to_bf16(b.z), f32_to_bf16(b.w) };
    *(u16x8*)((mat ? Yt : Xt) + (size_t)u * 8) = h;   // 16 B/thread, block-contiguous

    // Fused exact-f32 row norms. Each row's 16 contributors are lanes
    // {l16, l16+16, l16+32, l16+48} of each of the 4 waves (quad via shfl,
    // ks via LDS). One block covers exactly 16 complete rows.
    float s = a.x*a.x + a.y*a.y + a.z*a.z + a.w*a.w
            + b.x*b.x + b.y*b.y + b.z*b.z + b.w*b.w;
    s += __shfl_xor(s, 16, 64);
    s += __shfl_xor(s, 32, 64);
    if ((t & 63) < 16) part[t >> 6][t & 15] = s;
    __syncthreads();
    if (t < 16) {
        float tot = part[0][t] + part[1][t] + part[2][t] + part[3][t];
        nrm[(mat ? NROW : 0) + tt * 128 + ti * 16 + t] = tot;
    }
}

// 128x128 output tile per block. NO LDS, NO BARRIERS: fragments are loaded
// directly from the pre-packed global layout (each load = 1 KB coalesced,
// L2-resident thanks to the XCD swizzle), MFMA'd, and stored. Pure stream.
__global__ __launch_bounds__(256, 3) void rbf_main(const unsigned short* __restrict__ Xt,
                                                   const unsigned short* __restrict__ Yt,
                                                   const float* __restrict__ sigma,
                                                   const float* __restrict__ nrm,
                                                   float* __restrict__ out) {
    const int t = threadIdx.x;

    // XCD swizzle: flat%8 -> XCD; each XCD's 512 blocks cover 8 row-tiles x all
    // 64 col-tiles -> ~2.25 MB footprint, resident in its 4 MiB L2.
    const int flat = blockIdx.y * 64 + blockIdx.x;
    const int nf = (flat & 7) * 512 + (flat >> 3);
    const int tyi = nf >> 6;              // X row tile
    const int txi = nf & 63;              // Y row tile (out col tile)
    const int row0 = tyi * TILE;
    const int col0 = txi * TILE;

    const int w = t >> 6, ln = t & 63;
    const int quad = ln >> 4, l16 = ln & 15;
    const int wr2 = (w >> 1) * 4;   // X-dim: this wave's first 16-row group
    const int wc2 = (w & 1) * 4;    // Y-dim half

    // Fragment base: unit = ((tile*8 + group)*4 + ks)*64 + ln ; byte = unit*16
    const char* xb = (const char*)Xt + ((size_t)((tyi * 8 + wr2) * 256 + ln)) * 16;
    const char* yb = (const char*)Yt + ((size_t)((txi * 8 + wc2) * 256 + ln)) * 16;

    f32x4 acc[4][4] = {};   // [ti = X-dim 16-frag][tj = Y-dim 16-frag]

    #pragma unroll
    for (int ks = 0; ks < 4; ++ks) {
        bf16x8 ax[4], by[4];
        #pragma unroll
        for (int ti = 0; ti < 4; ++ti)
            ax[ti] = *(const bf16x8*)(xb + ti * 4096 + ks * 1024);
        #pragma unroll
        for (int tj = 0; tj < 4; ++tj)
            by[tj] = *(const bf16x8*)(yb + tj * 4096 + ks * 1024);
        #pragma unroll
        for (int ti = 0; ti < 4; ++ti)
            #pragma unroll
            for (int tj = 0; tj < 4; ++tj)
                // A = Y frag (rows = out cols), B = X frag (cols = out rows)
                acc[ti][tj] = __builtin_amdgcn_mfma_f32_16x16x32_bf16(by[tj], ax[ti], acc[ti][tj], 0, 0, 0);
    }

    const float s2 = sigma[0] * sigma[0] + 1e-9f;
    const float cexp = -1.4426950408889634f / s2;   // exp(-d/s2) = exp2(d * cexp)

    // D layout: col(n) = l16 -> X row; row(m) = quad*4 + r -> Y row (out column).
    float x2r[4];
    #pragma unroll
    for (int ti = 0; ti < 4; ++ti)
        x2r[ti] = nrm[row0 + wr2 * 16 + ti * 16 + l16];

    #pragma unroll
    for (int tj = 0; tj < 4; ++tj) {
        f32x4 y2v = *(const f32x4*)(nrm + NROW + col0 + wc2 * 16 + tj * 16 + quad * 4);
        size_t gcol = (size_t)(col0 + wc2 * 16 + tj * 16 + quad * 4);
        #pragma unroll
        for (int ti = 0; ti < 4; ++ti) {
            f32x4 v;
            #pragma unroll
            for (int r = 0; r < 4; ++r) {
                float d = x2r[ti] + y2v[r] - 2.0f * acc[ti][tj][r];
                v[r] = __builtin_amdgcn_exp2f(d * cexp);
            }
            size_t grow = (size_t)(row0 + wr2 * 16 + ti * 16 + l16);
            *(f32x4*)(out + grow * OUT_LD + gcol) = v;
        }
    }
}

extern "C" void kernel_launch(void* const* d_in, const int* in_sizes, int n_in,
                              void* d_out, int out_size, void* d_ws, size_t ws_size,
                              hipStream_t stream) {
    const float* X = (const float*)d_in[0];
    const float* Y = (const float*)d_in[1];
    const float* sigma = (const float*)d_in[2];
    float* nrm = (float*)d_ws;                                   // 16384 f32 = 64 KB
    unsigned short* Xt = (unsigned short*)((char*)d_ws + 65536); // 2 MB bf16 fragments
    unsigned short* Yt = Xt + (size_t)131072 * 8;                // 2 MB bf16 fragments
    float* out = (float*)d_out;

    rbf_pack<<<1024, 256, 0, stream>>>(X, Y, Xt, Yt, nrm);
    rbf_main<<<dim3(MROW / TILE, NROW / TILE), 256, 0, stream>>>(Xt, Yt, sigma, nrm, out);
}